// Round 5
// baseline (3739.857 us; speedup 1.0000x reference)
//
#include <hip/hip_runtime.h>
#include <hip/hip_bf16.h>
#include <math.h>

constexpr int B = 32, S = 64, T = 64, H = 512, V = 32000;
constexpr int G3 = 3 * H;     // 1536
constexpr int BT = B * T;     // 2048

// ---- workspace layout (float offsets) ----
constexpr size_t UAK_OFF    = 0;          // [B*S*H]     1,048,576
constexpr size_t GIE_OFF    = 1048576;    // [B*T*G3]    3,145,728
constexpr size_t KWT_OFF    = 4194304;    // [B*G3*S]    3,145,728
constexpr size_t WROT_OFF   = 7340032;    // [T*B*S]     131,072   (rotating attn weights)
constexpr size_t WAT_OFF    = 7471104;    // WaT [H*H]   262,144
constexpr size_t HALL_OFF   = 8192000;    // [(T+1)*B*H] 1,064,960 (beyond OWBF zone)
constexpr size_t ROWIDX_OFF = 9256960;    // 2048 ints
constexpr size_t FLG_OFF    = 9259008;    // 4096 ints (T x 64: [0:32)=W flags, [32:64)=B flags)
constexpr size_t HBF_OFF    = 9263104;    // bf16 [B*T*H] = 524,288 float slots
constexpr size_t OWBF_OFF   = 0;          // bf16 [V*H] = 8,192,000 float slots; aliases
                                          // UAK/GIE/KWT/WROT/WAT (all dead post-recurrence)

typedef __attribute__((ext_vector_type(8))) short bf16x8;
typedef __attribute__((ext_vector_type(4))) float f32x4;

__device__ __forceinline__ float fast_tanh(float x) {
  float ax = fabsf(x);
  float e = __expf(-2.f * ax);
  float r = (1.f - e) / (1.f + e);
  return x < 0.f ? -r : r;
}
__device__ __forceinline__ float fast_sig(float x) {
  return 1.f / (1.f + __expf(-x));
}
// load that bypasses L1 AND L2 (reads the coherence point / LLC)
__device__ __forceinline__ int load_coh_i32(const int* p) {
  int v;
  asm volatile("global_load_dword %0, %1, off sc0 sc1\n\ts_waitcnt vmcnt(0)"
               : "=v"(v) : "v"(p) : "memory");
  return v;
}
__device__ __forceinline__ void store_coh_f32(float* p, float v) {
  asm volatile("global_store_dword %0, %1, off sc0 sc1" :: "v"(p), "v"(v) : "memory");
}

// -------------------- init: h0, token row indices, flags --------------------
__global__ void k_init(const float* __restrict__ eh, const int* __restrict__ tgt,
                       float* __restrict__ ws) {
  int i = blockIdx.x * 256 + threadIdx.x;      // grid 64*256 = 16384
  if (i < B * H) ws[HALL_OFF + i] = eh[i];
  if (i < BT) {
    int b = i / T, t = i % T;
    ((int*)(ws + ROWIDX_OFF))[i] = (t == 0) ? 0 : tgt[b * T + t - 1];
  }
  if (i < 4096) ((int*)(ws + FLG_OFF))[i] = 0;
}

// -------------------- 512x512 transpose: WaT[k][j] = Wa_w[j][k] --------------------
__global__ __launch_bounds__(256) void k_transpose(const float* __restrict__ A,
                                                   float* __restrict__ At) {
  __shared__ float tile[32][33];
  int bx = blockIdx.x, by = blockIdx.y;
  int tx = threadIdx.x & 31, ty = threadIdx.x >> 5;
  for (int r = 0; r < 32; r += 8)
    tile[ty + r][tx] = A[(size_t)(by * 32 + ty + r) * 512 + bx * 32 + tx];
  __syncthreads();
  for (int r = 0; r < 32; r += 8)
    At[(size_t)(bx * 32 + ty + r) * 512 + by * 32 + tx] = tile[tx][ty + r];
}

// -------------------- out_w fp32 -> bf16 (runs AFTER recurrence; aliases ws) ----
__global__ void k_conv_outw(const float* __restrict__ w, ushort* __restrict__ o, int n4) {
  int i = blockIdx.x * blockDim.x + threadIdx.x;
  if (i < n4) {
    float4 v = *(const float4*)&w[(size_t)i * 4];
    ushort4 u;
    __hip_bfloat16 h0 = __float2bfloat16(v.x); u.x = *(ushort*)&h0;
    __hip_bfloat16 h1 = __float2bfloat16(v.y); u.y = *(ushort*)&h1;
    __hip_bfloat16 h2 = __float2bfloat16(v.z); u.z = *(ushort*)&h2;
    __hip_bfloat16 h3 = __float2bfloat16(v.w); u.w = *(ushort*)&h3;
    *(ushort4*)&o[(size_t)i * 4] = u;
  }
}

// -------- fp32 tiled GEMM, k-major LDS: C[m,n] = A[arow(m),:] . Bw[n,:] + bias[n] --------
__global__ __launch_bounds__(256) void k_gemm_at(
    const float* __restrict__ A, const float* __restrict__ Bw, int ldb,
    const float* __restrict__ bias, float* __restrict__ C,
    const int* __restrict__ rowidx, int N) {
  __shared__ float AsT[32][72];
  __shared__ float BsT[32][72];
  int tid = threadIdx.x;
  int bm = blockIdx.x, bn = blockIdx.y;
  int tr = tid >> 4, tc = tid & 15;
  float acc[4][4] = {};
  for (int k0 = 0; k0 < 512; k0 += 32) {
    __syncthreads();
#pragma unroll
    for (int i = 0; i < 2; i++) {
      int e = tid + i * 256;
      int row = e >> 3, c4 = (e & 7) * 4;
      int ar = bm * 64 + row;
      int arow = rowidx ? rowidx[ar] : ar;
      float4 v = *(const float4*)&A[(size_t)arow * 512 + k0 + c4];
      AsT[c4 + 0][row] = v.x; AsT[c4 + 1][row] = v.y;
      AsT[c4 + 2][row] = v.z; AsT[c4 + 3][row] = v.w;
      float4 u = *(const float4*)&Bw[(size_t)(bn * 64 + row) * ldb + k0 + c4];
      BsT[c4 + 0][row] = u.x; BsT[c4 + 1][row] = u.y;
      BsT[c4 + 2][row] = u.z; BsT[c4 + 3][row] = u.w;
    }
    __syncthreads();
#pragma unroll
    for (int kk = 0; kk < 32; kk++) {
      float4 a4 = *(const float4*)&AsT[kk][tr * 4];
      float4 b4 = *(const float4*)&BsT[kk][tc * 4];
      acc[0][0] += a4.x * b4.x; acc[0][1] += a4.x * b4.y; acc[0][2] += a4.x * b4.z; acc[0][3] += a4.x * b4.w;
      acc[1][0] += a4.y * b4.x; acc[1][1] += a4.y * b4.y; acc[1][2] += a4.y * b4.z; acc[1][3] += a4.y * b4.w;
      acc[2][0] += a4.z * b4.x; acc[2][1] += a4.z * b4.y; acc[2][2] += a4.z * b4.z; acc[2][3] += a4.z * b4.w;
      acc[3][0] += a4.w * b4.x; acc[3][1] += a4.w * b4.y; acc[3][2] += a4.w * b4.z; acc[3][3] += a4.w * b4.w;
    }
  }
#pragma unroll
  for (int i = 0; i < 4; i++) {
    int m = bm * 64 + tr * 4 + i;
#pragma unroll
    for (int j = 0; j < 4; j++) {
      int n = bn * 64 + tc * 4 + j;
      C[(size_t)m * N + n] = acc[i][j] + bias[n];
    }
  }
}

// -------- KWT[b, col, s] = sum_k W_ih[col, 512+k] * keys[b*64+s, k] --------
__global__ __launch_bounds__(256) void k_gemm_kwt(
    const float* __restrict__ W_ih, const float* __restrict__ keys,
    float* __restrict__ KWT) {
  __shared__ float AsT[32][72];
  __shared__ float BsT[32][72];
  int tid = threadIdx.x;
  int bm = blockIdx.x, b = blockIdx.y;
  int tr = tid >> 4, tc = tid & 15;
  float acc[4][4] = {};
  for (int k0 = 0; k0 < 512; k0 += 32) {
    __syncthreads();
#pragma unroll
    for (int i = 0; i < 2; i++) {
      int e = tid + i * 256;
      int row = e >> 3, c4 = (e & 7) * 4;
      float4 v = *(const float4*)&W_ih[(size_t)(bm * 64 + row) * 1024 + 512 + k0 + c4];
      AsT[c4 + 0][row] = v.x; AsT[c4 + 1][row] = v.y;
      AsT[c4 + 2][row] = v.z; AsT[c4 + 3][row] = v.w;
      float4 u = *(const float4*)&keys[(size_t)(b * 64 + row) * 512 + k0 + c4];
      BsT[c4 + 0][row] = u.x; BsT[c4 + 1][row] = u.y;
      BsT[c4 + 2][row] = u.z; BsT[c4 + 3][row] = u.w;
    }
    __syncthreads();
#pragma unroll
    for (int kk = 0; kk < 32; kk++) {
      float4 a4 = *(const float4*)&AsT[kk][tr * 4];
      float4 b4 = *(const float4*)&BsT[kk][tc * 4];
      acc[0][0] += a4.x * b4.x; acc[0][1] += a4.x * b4.y; acc[0][2] += a4.x * b4.z; acc[0][3] += a4.x * b4.w;
      acc[1][0] += a4.y * b4.x; acc[1][1] += a4.y * b4.y; acc[1][2] += a4.y * b4.z; acc[1][3] += a4.y * b4.w;
      acc[2][0] += a4.z * b4.x; acc[2][1] += a4.z * b4.y; acc[2][2] += a4.z * b4.z; acc[2][3] += a4.z * b4.w;
      acc[3][0] += a4.w * b4.x; acc[3][1] += a4.w * b4.y; acc[3][2] += a4.w * b4.z; acc[3][3] += a4.w * b4.w;
    }
  }
#pragma unroll
  for (int i = 0; i < 4; i++) {
    int m = bm * 64 + tr * 4 + i;
#pragma unroll
    for (int j = 0; j < 4; j++)
      KWT[((size_t)b * G3 + m) * S + tc * 4 + j] = acc[i][j];
  }
}

// -------------------- persistent recurrence --------------------
// grid 256 x 256 thr, all WGs loop t=0..63 inside the kernel (L2 stays warm).
// Roles: WG w<32 additionally = attn WG for batch b=w (full q via WaT, scores,
// softmax, write rotating WROT_t + flagW). ALL WGs: gh = W_hh.h (overlaps attn),
// then poll flagW, stage weights, KWT/GIE combine, write h_{t+1} (sc0sc1,
// rotating) + flagB. Polls use L2-bypass loads; data reads are normal cached
// loads of first-touch-fresh rotating addresses.
__global__ __launch_bounds__(256) void k_recur(
    const float* __restrict__ Wa_b,
    const float* __restrict__ Va_w, const float* __restrict__ Va_b,
    const float* __restrict__ W_hh, const float* __restrict__ b_hh,
    float* __restrict__ ws, float* __restrict__ attn_out) {
  const int w = blockIdx.x;        // 0..255
  const int tid = threadIdx.x;
  int* flg = (int*)(ws + FLG_OFF);
  __hip_bfloat16* HBF = (__hip_bfloat16*)(ws + HBF_OFF);
  const float* WaT = ws + WAT_OFF;

  __shared__ float sh[512];        // h[b] (attn WGs)
  __shared__ float sq[512];        // q
  __shared__ float sp[64][4];      // score partials
  __shared__ float swAll[32][64];  // staged weights, all b
  __shared__ float ga[4][2][32];   // gate combine

  for (int t = 0; t < T; ++t) {
    const float* hcur = ws + HALL_OFF + (size_t)t * (B * H);
    // ---- wait for h_t (t>0) ----
    if (t > 0) {
      const int* fb = flg + (size_t)(t - 1) * 64 + 32;
      if (tid < 32)
        while (load_coh_i32(&fb[tid]) != 8) __builtin_amdgcn_s_sleep(1);
    }
    __syncthreads();

    if (w < 32) {
      // ===== attention for batch b=w =====
      sh[tid] = hcur[w * H + tid];
      sh[tid + 256] = hcur[w * H + tid + 256];
      __syncthreads();
      {  // q[2tid], q[2tid+1] = h . WaT cols (coalesced float2 loads)
        const float* wp = WaT + 2 * tid;
        float a00 = 0.f, a01 = 0.f, a10 = 0.f, a11 = 0.f;
#pragma unroll 4
        for (int k = 0; k < 512; k += 2) {
          float hk0 = sh[k], hk1 = sh[k + 1];
          float2 w0 = *(const float2*)&wp[(size_t)k * 512];
          float2 w1 = *(const float2*)&wp[(size_t)(k + 1) * 512];
          a00 += hk0 * w0.x; a01 += hk0 * w0.y;
          a10 += hk1 * w1.x; a11 += hk1 * w1.y;
        }
        sq[2 * tid] = a00 + a10 + Wa_b[2 * tid];
        sq[2 * tid + 1] = a01 + a11 + Wa_b[2 * tid + 1];
      }
      __syncthreads();
      {  // score partials: thread (s, jq) over 128 j's
        int s = tid >> 2, jq = tid & 3;
        const float* uk = ws + UAK_OFF + ((size_t)(w * 64 + s)) * H + jq * 128;
        const float* va = Va_w + jq * 128;
        const float* qq = sq + jq * 128;
        float acc = 0.f;
#pragma unroll 4
        for (int i = 0; i < 128; i += 4) {
          float4 u4 = *(const float4*)&uk[i];
          float4 v4 = *(const float4*)&va[i];
          acc += v4.x * fast_tanh(qq[i] + u4.x) + v4.y * fast_tanh(qq[i + 1] + u4.y)
               + v4.z * fast_tanh(qq[i + 2] + u4.z) + v4.w * fast_tanh(qq[i + 3] + u4.w);
        }
        sp[s][jq] = acc;
      }
      __syncthreads();
      if (tid < 64) {
        float v = sp[tid][0] + sp[tid][1] + sp[tid][2] + sp[tid][3] + Va_b[0];
        float m = v;
        for (int o = 32; o; o >>= 1) m = fmaxf(m, __shfl_xor(m, o, 64));
        float e = __expf(v - m);
        float su = e;
        for (int o = 32; o; o >>= 1) su += __shfl_xor(su, o, 64);
        float wt = e / su;
        attn_out[((size_t)w * T + t) * S + tid] = wt;
        store_coh_f32(ws + WROT_OFF + ((size_t)t * B + w) * S + tid, wt);
      }
      if (tid == 0) {   // weights stored by wave 0 only -> its vmcnt covers them
        asm volatile("s_waitcnt vmcnt(0)" ::: "memory");
        __hip_atomic_fetch_add(&flg[(size_t)t * 64 + w], 1,
                               __ATOMIC_RELAXED, __HIP_MEMORY_SCOPE_AGENT);
      }
    }

    // ===== gh = W_hh . h_t for this WG's 6 gate-cols (h-cols {2w, 2w+1}) =====
    float gh = 0.f; int col = 0, gb = 0, gate = 0, jl = 0;
    if (tid < 192) {
      int c = tid >> 5; gb = tid & 31;
      gate = c >> 1; jl = c & 1;
      col = gate * 512 + 2 * w + jl;
      const float* wr = W_hh + (size_t)col * H;
      const float* hb = hcur + gb * H;
#pragma unroll 8
      for (int k = 0; k < 512; k += 4) {
        float4 w4 = *(const float4*)&wr[k];
        float4 h4 = *(const float4*)&hb[k];
        gh += w4.x * h4.x + w4.y * h4.y + w4.z * h4.z + w4.w * h4.w;
      }
      gh += b_hh[col];
    }
    // ---- wait attention weights ----
    {
      const int* fw = flg + (size_t)t * 64;
      if (tid < 32)
        while (load_coh_i32(&fw[tid]) != 1) __builtin_amdgcn_s_sleep(1);
    }
    __syncthreads();
    {  // stage all 32 weight rows (2048 floats)
      const float* wsrc = ws + WROT_OFF + (size_t)t * B * S;
      float4 v0 = *(const float4*)&wsrc[tid * 8];
      float4 v1 = *(const float4*)&wsrc[tid * 8 + 4];
      *(float4*)(&swAll[0][0] + tid * 8) = v0;
      *(float4*)(&swAll[0][0] + tid * 8 + 4) = v1;
    }
    __syncthreads();
    if (tid < 192) {  // gi = GIE + KWT . w ; combine with gh
      const float* kw = ws + KWT_OFF + ((size_t)gb * G3 + col) * 64;
      const float* wrow = &swAll[gb][0];
      float gic = 0.f;
#pragma unroll
      for (int s4 = 0; s4 < 64; s4 += 4) {
        float4 k4 = *(const float4*)&kw[s4];
        gic += k4.x * wrow[s4] + k4.y * wrow[s4 + 1] + k4.z * wrow[s4 + 2] + k4.w * wrow[s4 + 3];
      }
      float gi = ws[GIE_OFF + ((size_t)gb * T + t) * G3 + col] + gic;
      if (gate == 0) ga[0][jl][gb] = gi + gh;
      else if (gate == 1) ga[1][jl][gb] = gi + gh;
      else { ga[2][jl][gb] = gi; ga[3][jl][gb] = gh; }
    }
    __syncthreads();
    if (tid < 64) {  // GRU update, h-cols {2w, 2w+1} x 32 b  (wave 0)
      int b2 = tid >> 1, l2 = tid & 1;
      float r = fast_sig(ga[0][l2][b2]);
      float z = fast_sig(ga[1][l2][b2]);
      float n = fast_tanh(ga[2][l2][b2] + r * ga[3][l2][b2]);
      float hold = hcur[b2 * H + 2 * w + l2];
      float hn = (1.f - z) * n + z * hold;
      store_coh_f32(ws + HALL_OFF + (size_t)(t + 1) * B * H + b2 * H + 2 * w + l2, hn);
      HBF[((size_t)b2 * T + t) * H + 2 * w + l2] = __float2bfloat16(hn);
    }
    if (tid == 0) {   // h stores were all in wave 0
      asm volatile("s_waitcnt vmcnt(0)" ::: "memory");
      __hip_atomic_fetch_add(&flg[(size_t)t * 64 + 32 + (w >> 3)], 1,
                             __ATOMIC_RELAXED, __HIP_MEMORY_SCOPE_AGENT);
    }
    // next iteration's pollB + __syncthreads guards LDS reuse across steps
  }
}

// -------------------- bf16 MFMA out-projection: [2048,512] x [32000,512]^T --------------------
__global__ __launch_bounds__(256) void k_outgemm(
    const __hip_bfloat16* __restrict__ Abf, const __hip_bfloat16* __restrict__ Bbf,
    const float* __restrict__ bias, float* __restrict__ Cmat) {
  constexpr int LDT = 40;
  __shared__ __align__(16) short As[128 * LDT];
  __shared__ __align__(16) short Bs[128 * LDT];
  int bm = blockIdx.y, bn = blockIdx.x;
  int tid = threadIdx.x;
  int lane = tid & 63, wid = tid >> 6;
  int wm = wid >> 1, wn = wid & 1;
  f32x4 acc[4][4] = {};
  int srow = tid >> 1, shalf = tid & 1;
  for (int k0 = 0; k0 < 512; k0 += 32) {
    const float4* ga = (const float4*)&Abf[(size_t)(bm * 128 + srow) * 512 + k0 + shalf * 16];
    const float4* gb = (const float4*)&Bbf[(size_t)(bn * 128 + srow) * 512 + k0 + shalf * 16];
    float4 va0 = ga[0], va1 = ga[1];
    float4 vb0 = gb[0], vb1 = gb[1];
    __syncthreads();
    *(float4*)&As[srow * LDT + shalf * 16] = va0;
    *(float4*)&As[srow * LDT + shalf * 16 + 8] = va1;
    *(float4*)&Bs[srow * LDT + shalf * 16] = vb0;
    *(float4*)&Bs[srow * LDT + shalf * 16 + 8] = vb1;
    __syncthreads();
    int kc = lane >> 4, rl = lane & 15;
    bf16x8 af[4], bfv[4];
#pragma unroll
    for (int f = 0; f < 4; f++) {
      af[f] = *(const bf16x8*)&As[(wm * 64 + f * 16 + rl) * LDT + kc * 8];
      bfv[f] = *(const bf16x8*)&Bs[(wn * 64 + f * 16 + rl) * LDT + kc * 8];
    }
#pragma unroll
    for (int i = 0; i < 4; i++)
#pragma unroll
      for (int j = 0; j < 4; j++)
        acc[i][j] = __builtin_amdgcn_mfma_f32_16x16x32_bf16(af[i], bfv[j], acc[i][j], 0, 0, 0);
  }
  int cl = lane & 15, rg = lane >> 4;
#pragma unroll
  for (int i = 0; i < 4; i++) {
    int m = bm * 128 + wm * 64 + i * 16 + rg * 4;
#pragma unroll
    for (int j = 0; j < 4; j++) {
      int n = bn * 128 + wn * 64 + j * 16 + cl;
      float bv = bias[n];
#pragma unroll
      for (int r = 0; r < 4; r++)
        Cmat[(size_t)(m + r) * V + n] = acc[i][j][r] + bv;
    }
  }
}

// -------------------- in-place log_softmax (online stats, 2 passes) --------------------
__global__ __launch_bounds__(256) void k_logsoftmax(float* __restrict__ Cmat) {
  int row = blockIdx.x;
  float* p = Cmat + (size_t)row * V;
  int tid = threadIdx.x;
  __shared__ float sm[4], ss[4];
  float m = -1e30f, s = 0.f;
  for (int i = tid * 4; i < V; i += 1024) {
    float4 v = *(const float4*)&p[i];
    float m4 = fmaxf(fmaxf(v.x, v.y), fmaxf(v.z, v.w));
    float nm = fmaxf(m, m4);
    s = s * __expf(m - nm) + __expf(v.x - nm) + __expf(v.y - nm)
      + __expf(v.z - nm) + __expf(v.w - nm);
    m = nm;
  }
  for (int o = 32; o; o >>= 1) {
    float om = __shfl_xor(m, o, 64), os = __shfl_xor(s, o, 64);
    float nm = fmaxf(m, om);
    s = s * __expf(m - nm) + os * __expf(om - nm);
    m = nm;
  }
  if ((tid & 63) == 0) { sm[tid >> 6] = m; ss[tid >> 6] = s; }
  __syncthreads();
  float M = fmaxf(fmaxf(sm[0], sm[1]), fmaxf(sm[2], sm[3]));
  float Ssum = ss[0] * __expf(sm[0] - M) + ss[1] * __expf(sm[1] - M)
             + ss[2] * __expf(sm[2] - M) + ss[3] * __expf(sm[3] - M);
  float lse = M + __logf(Ssum);
  for (int i = tid * 4; i < V; i += 1024) {
    float4 v = *(const float4*)&p[i];
    v.x -= lse; v.y -= lse; v.z -= lse; v.w -= lse;
    *(float4*)&p[i] = v;
  }
}

__global__ void k_copy_ht(const float* __restrict__ hsrc, float* __restrict__ o) {
  int i = blockIdx.x * 256 + threadIdx.x;
  if (i < B * H) o[i] = hsrc[i];
}

extern "C" void kernel_launch(void* const* d_in, const int* in_sizes, int n_in,
                              void* d_out, int out_size, void* d_ws, size_t ws_size,
                              hipStream_t stream) {
  (void)in_sizes; (void)n_in; (void)out_size; (void)ws_size;
  const float* keys = (const float*)d_in[0];
  const float* ehid = (const float*)d_in[1];
  const int* tgt    = (const int*)d_in[2];
  const float* emb  = (const float*)d_in[4];
  const float* Wa_w = (const float*)d_in[5];
  const float* Wa_b = (const float*)d_in[6];
  const float* Ua_w = (const float*)d_in[7];
  const float* Ua_b = (const float*)d_in[8];
  const float* Va_w = (const float*)d_in[9];
  const float* Va_b = (const float*)d_in[10];
  const float* W_ih = (const float*)d_in[11];
  const float* W_hh = (const float*)d_in[12];
  const float* b_ih = (const float*)d_in[13];
  const float* b_hh = (const float*)d_in[14];
  const float* out_w = (const float*)d_in[15];
  const float* out_b = (const float*)d_in[16];
  float* ws = (float*)d_ws;
  float* out = (float*)d_out;
  float* logits = out;                              // [B,T,V]
  float* ht_out = out + (size_t)B * T * V;          // [1,B,H]
  float* attn_out = ht_out + (size_t)B * H;         // [B,T,S]

  hipLaunchKernelGGL(k_init, dim3(64), dim3(256), 0, stream, ehid, tgt, ws);
  hipLaunchKernelGGL(k_transpose, dim3(16, 16), dim3(256), 0, stream,
                     Wa_w, ws + WAT_OFF);
  // Ua_keys = keys @ Ua_w.T + Ua_b
  hipLaunchKernelGGL(k_gemm_at, dim3(32, 8), dim3(256), 0, stream,
                     keys, Ua_w, 512, Ua_b, ws + UAK_OFF, (const int*)nullptr, 512);
  // Gi_e = emb[tokens] @ W_ih[:, :512].T + b_ih
  hipLaunchKernelGGL(k_gemm_at, dim3(32, 24), dim3(256), 0, stream,
                     emb, W_ih, 1024, b_ih, ws + GIE_OFF, (const int*)(ws + ROWIDX_OFF), G3);
  // KWT[b,col,s] = W_ih_ctx @ keys[b]^T
  hipLaunchKernelGGL(k_gemm_kwt, dim3(24, 32), dim3(256), 0, stream,
                     W_ih, keys, ws + KWT_OFF);
  // persistent recurrence: ONE launch for all 64 steps
  hipLaunchKernelGGL(k_recur, dim3(256), dim3(256), 0, stream,
                     Wa_b, Va_w, Va_b, W_hh, b_hh, ws, attn_out);
  hipLaunchKernelGGL(k_copy_ht, dim3(64), dim3(256), 0, stream,
                     ws + HALL_OFF + (size_t)T * B * H, ht_out);
  // bf16 out_w copy into the (now dead) precompute region
  hipLaunchKernelGGL(k_conv_outw, dim3((V * H / 4 + 255) / 256), dim3(256), 0, stream,
                     out_w, (ushort*)(ws + OWBF_OFF), V * H / 4);
  hipLaunchKernelGGL(k_outgemm, dim3(250, 16), dim3(256), 0, stream,
                     (const __hip_bfloat16*)(ws + HBF_OFF),
                     (const __hip_bfloat16*)(ws + OWBF_OFF), out_b, logits);
  hipLaunchKernelGGL(k_logsoftmax, dim3(BT), dim3(256), 0, stream, logits);
}

// Round 6
// 2695.237 us; speedup vs baseline: 1.3876x; 1.3876x over previous
//
#include <hip/hip_runtime.h>
#include <hip/hip_bf16.h>
#include <math.h>

constexpr int B = 32, S = 64, T = 64, H = 512, V = 32000;
constexpr int G3 = 3 * H;     // 1536
constexpr int BT = B * T;     // 2048

// ---- workspace layout (float offsets) ----
constexpr size_t UAK_OFF    = 0;          // [B*S*H]        1,048,576
constexpr size_t GIE_OFF    = 1048576;    // [T][G3][B]     3,145,728
constexpr size_t SCP_OFF    = 4194304;    // [T][B][8][64]  1,048,576 (rotating score partials)
constexpr size_t CTX_OFF    = 5242880;    // [T][B][512]    1,048,576 (rotating ctx)
constexpr size_t HALL_OFF   = 8192000;    // [(T+1)*B*H]    1,064,960
constexpr size_t ROWIDX_OFF = 9256960;    // 2048 ints
constexpr size_t FLG_OFF    = 9259008;    // T*320 ints = 20,480
constexpr size_t HBF_OFF    = 9279488;    // bf16 [B*T*H] = 524,288 float slots
constexpr size_t OWBF_OFF   = 0;          // bf16 [V*H] = 8,192,000 float slots;
                                          // aliases UAK/GIE/SCP/CTX (dead post-recurrence)

typedef __attribute__((ext_vector_type(8))) short bf16x8;
typedef __attribute__((ext_vector_type(4))) float f32x4;

__device__ __forceinline__ float fast_tanh(float x) {
  float ax = fabsf(x);
  float e = __expf(-2.f * ax);
  float r = (1.f - e) / (1.f + e);
  return x < 0.f ? -r : r;
}
__device__ __forceinline__ float fast_sig(float x) {
  return 1.f / (1.f + __expf(-x));
}
// load/store that bypass L1+L2 (coherence point / LLC)
__device__ __forceinline__ int load_coh_i32(const int* p) {
  int v;
  asm volatile("global_load_dword %0, %1, off sc0 sc1\n\ts_waitcnt vmcnt(0)"
               : "=v"(v) : "v"(p) : "memory");
  return v;
}
__device__ __forceinline__ void store_coh_f32(float* p, float v) {
  asm volatile("global_store_dword %0, %1, off sc0 sc1" :: "v"(p), "v"(v) : "memory");
}
__device__ __forceinline__ void store_coh_f32x4(float* p, f32x4 v) {
  asm volatile("global_store_dwordx4 %0, %1, off sc0 sc1" :: "v"(p), "v"(v) : "memory");
}

// -------------------- init: h0, token row indices, flags --------------------
__global__ void k_init(const float* __restrict__ eh, const int* __restrict__ tgt,
                       float* __restrict__ ws) {
  int i = blockIdx.x * 256 + threadIdx.x;      // grid 128*256 = 32768
  if (i < B * H) ws[HALL_OFF + i] = eh[i];
  if (i < BT) {
    int b = i / T, t = i % T;
    ((int*)(ws + ROWIDX_OFF))[i] = (t == 0) ? 0 : tgt[b * T + t - 1];
  }
  if (i < T * 320) ((int*)(ws + FLG_OFF))[i] = 0;
}

// -------------------- out_w fp32 -> bf16 (runs AFTER recurrence; aliases ws) ----
__global__ void k_conv_outw(const float* __restrict__ w, ushort* __restrict__ o, int n4) {
  int i = blockIdx.x * blockDim.x + threadIdx.x;
  if (i < n4) {
    float4 v = *(const float4*)&w[(size_t)i * 4];
    ushort4 u;
    __hip_bfloat16 h0 = __float2bfloat16(v.x); u.x = *(ushort*)&h0;
    __hip_bfloat16 h1 = __float2bfloat16(v.y); u.y = *(ushort*)&h1;
    __hip_bfloat16 h2 = __float2bfloat16(v.z); u.z = *(ushort*)&h2;
    __hip_bfloat16 h3 = __float2bfloat16(v.w); u.w = *(ushort*)&h3;
    *(ushort4*)&o[(size_t)i * 4] = u;
  }
}

// -------- fp32 tiled GEMM, k-major LDS: C = A[arow(m),:] . Bw[n,:] + bias[n] --------
// gie_t: write transposed layout C[((m%T)*G3 + n)*B + m/T]
__global__ __launch_bounds__(256) void k_gemm_at(
    const float* __restrict__ A, const float* __restrict__ Bw, int ldb,
    const float* __restrict__ bias, float* __restrict__ C,
    const int* __restrict__ rowidx, int N, int gie_t) {
  __shared__ float AsT[32][72];
  __shared__ float BsT[32][72];
  int tid = threadIdx.x;
  int bm = blockIdx.x, bn = blockIdx.y;
  int tr = tid >> 4, tc = tid & 15;
  float acc[4][4] = {};
  for (int k0 = 0; k0 < 512; k0 += 32) {
    __syncthreads();
#pragma unroll
    for (int i = 0; i < 2; i++) {
      int e = tid + i * 256;
      int row = e >> 3, c4 = (e & 7) * 4;
      int ar = bm * 64 + row;
      int arow = rowidx ? rowidx[ar] : ar;
      float4 v = *(const float4*)&A[(size_t)arow * 512 + k0 + c4];
      AsT[c4 + 0][row] = v.x; AsT[c4 + 1][row] = v.y;
      AsT[c4 + 2][row] = v.z; AsT[c4 + 3][row] = v.w;
      float4 u = *(const float4*)&Bw[(size_t)(bn * 64 + row) * ldb + k0 + c4];
      BsT[c4 + 0][row] = u.x; BsT[c4 + 1][row] = u.y;
      BsT[c4 + 2][row] = u.z; BsT[c4 + 3][row] = u.w;
    }
    __syncthreads();
#pragma unroll
    for (int kk = 0; kk < 32; kk++) {
      float4 a4 = *(const float4*)&AsT[kk][tr * 4];
      float4 b4 = *(const float4*)&BsT[kk][tc * 4];
      acc[0][0] += a4.x * b4.x; acc[0][1] += a4.x * b4.y; acc[0][2] += a4.x * b4.z; acc[0][3] += a4.x * b4.w;
      acc[1][0] += a4.y * b4.x; acc[1][1] += a4.y * b4.y; acc[1][2] += a4.y * b4.z; acc[1][3] += a4.y * b4.w;
      acc[2][0] += a4.z * b4.x; acc[2][1] += a4.z * b4.y; acc[2][2] += a4.z * b4.z; acc[2][3] += a4.z * b4.w;
      acc[3][0] += a4.w * b4.x; acc[3][1] += a4.w * b4.y; acc[3][2] += a4.w * b4.z; acc[3][3] += a4.w * b4.w;
    }
  }
#pragma unroll
  for (int i = 0; i < 4; i++) {
    int m = bm * 64 + tr * 4 + i;
#pragma unroll
    for (int j = 0; j < 4; j++) {
      int n = bn * 64 + tc * 4 + j;
      float val = acc[i][j] + bias[n];
      if (gie_t) C[((size_t)(m % T) * G3 + n) * B + (m / T)] = val;
      else       C[(size_t)m * N + n] = val;
    }
  }
}

// -------------------- persistent recurrence (v2: LDS-weight-stationary) --------------------
// 256 WGs x 256 thr, 1 WG/CU. Per WG static LDS: 6 W_ih_ctx rows + 6 W_hh rows
// (cols {2w,2w+1} x 3 gates) + UAK slice for producer (bp=w>>3, gp=w&7) + Va slice.
// Per step: [poll h] -> phase1 (q-slice + partial scores; SCP+flag) ->
// phase2 (w<32: sum partials, softmax, attn_out, ctx = w.keys; CTX+flag) ->
// phase3 (gh from LDS W_hh, poll ctx, gic from LDS W_ih_ctx, + GIE -> GRU update;
// h store + flag). All handshakes: sc0sc1 stores + vmcnt + relaxed agent add;
// polls via L2-bypass loads; data reads are first-touch-fresh rotating addresses.
__global__ __launch_bounds__(256) void k_recur(
    const float* __restrict__ keys,
    const float* __restrict__ Wa_w, const float* __restrict__ Wa_b,
    const float* __restrict__ Va_w, const float* __restrict__ Va_b,
    const float* __restrict__ W_ih, const float* __restrict__ W_hh,
    const float* __restrict__ b_hh,
    float* __restrict__ ws, float* __restrict__ attn_out) {
  const int w = blockIdx.x;        // 0..255
  const int tid = threadIdx.x;
  const int bp = w >> 3, gp = w & 7;   // producer identity
  int* flg = (int*)(ws + FLG_OFF);
  __hip_bfloat16* HBF = (__hip_bfloat16*)(ws + HBF_OFF);

  __shared__ float sWih[6][512];   // W_ih ctx-half rows (12KB)
  __shared__ float sWhh[6][512];   // W_hh rows (12KB)
  __shared__ float sUAK[64][68];   // UAK[bp, s, gp*64+jl] (17.4KB)
  __shared__ float sVa[64];
  __shared__ float sh[512];        // staged h[bp]
  __shared__ float sq[64];         // q slice
  __shared__ float qp[64][4];
  __shared__ float sp[64][4];
  __shared__ float swt[64];        // softmax weights (attn WGs)
  __shared__ float sctx[512];
  __shared__ float ga[4][2][32];

  // ---- one-time staging ----
  for (int c = 0; c < 6; c++) {
    int col0 = (c >> 1) * 512 + 2 * w + (c & 1);
    for (int k = tid; k < 512; k += 256) {
      sWih[c][k] = W_ih[(size_t)col0 * 1024 + 512 + k];
      sWhh[c][k] = W_hh[(size_t)col0 * 512 + k];
    }
  }
  {
    int s = tid >> 2, ch = tid & 3;
    const float* up = ws + UAK_OFF + ((size_t)(bp * 64 + s)) * H + gp * 64 + ch * 16;
#pragma unroll
    for (int i = 0; i < 16; i += 4)
      *(float4*)&sUAK[s][ch * 16 + i] = *(const float4*)&up[i];
  }
  if (tid < 64) sVa[tid] = Va_w[gp * 64 + tid];
  __syncthreads();

  for (int t = 0; t < T; ++t) {
    const float* hcur = ws + HALL_OFF + (size_t)t * (B * H);
    // ---- wait for h_t ----
    if (t > 0) {
      const int* fb = flg + (size_t)(t - 1) * 320 + 288;
      if (tid < 32)
        while (load_coh_i32(&fb[tid]) != 8) __builtin_amdgcn_s_sleep(1);
    }
    __syncthreads();

    // ===== phase 1: producer (bp, gp): q slice + partial scores =====
    sh[tid] = hcur[bp * H + tid];
    sh[tid + 256] = hcur[bp * H + 256 + tid];
    __syncthreads();
    {
      int jl = tid >> 2, kq = tid & 3;
      const float* wrow = Wa_w + (size_t)(gp * 64 + jl) * H + kq * 128;
      const float* hv = sh + kq * 128;
      float acc = 0.f;
#pragma unroll
      for (int i = 0; i < 128; i += 4) {
        float4 w4 = *(const float4*)&wrow[i];
        acc += w4.x * hv[i] + w4.y * hv[i + 1] + w4.z * hv[i + 2] + w4.w * hv[i + 3];
      }
      qp[jl][kq] = acc;
    }
    __syncthreads();
    if (tid < 64)
      sq[tid] = qp[tid][0] + qp[tid][1] + qp[tid][2] + qp[tid][3] + Wa_b[gp * 64 + tid];
    __syncthreads();
    {
      int s = tid >> 2, jc = tid & 3;
      const float* qq = sq + jc * 16;
      const float* va = sVa + jc * 16;
      float accs = 0.f;
#pragma unroll
      for (int i = 0; i < 16; i += 4) {
        float4 u4 = *(const float4*)&sUAK[s][jc * 16 + i];
        accs += va[i] * fast_tanh(qq[i] + u4.x) + va[i + 1] * fast_tanh(qq[i + 1] + u4.y)
              + va[i + 2] * fast_tanh(qq[i + 2] + u4.z) + va[i + 3] * fast_tanh(qq[i + 3] + u4.w);
      }
      sp[s][jc] = accs;
    }
    __syncthreads();
    if (tid < 64) {
      float val = sp[tid][0] + sp[tid][1] + sp[tid][2] + sp[tid][3];
      if (gp == 0) val += Va_b[0];
      store_coh_f32(ws + SCP_OFF + (((size_t)t * B + bp) * 8 + gp) * 64 + tid, val);
    }
    if (tid == 0) {
      asm volatile("s_waitcnt vmcnt(0)" ::: "memory");
      __hip_atomic_fetch_add(&flg[(size_t)t * 320 + bp * 8 + gp], 1,
                             __ATOMIC_RELAXED, __HIP_MEMORY_SCOPE_AGENT);
    }

    // ===== phase 2: attn WG (w<32, b=w): softmax + ctx =====
    if (w < 32) {
      {
        const int* fp = flg + (size_t)t * 320 + w * 8;
        if (tid < 8)
          while (load_coh_i32(&fp[tid]) == 0) __builtin_amdgcn_s_sleep(1);
      }
      __syncthreads();
      if (tid < 64) {
        const float* spp = ws + SCP_OFF + ((size_t)t * B + w) * 512 + tid;
        float v = spp[0] + spp[64] + spp[128] + spp[192]
                + spp[256] + spp[320] + spp[384] + spp[448];
        float m = v;
        for (int o = 32; o; o >>= 1) m = fmaxf(m, __shfl_xor(m, o, 64));
        float e = __expf(v - m);
        float su = e;
        for (int o = 32; o; o >>= 1) su += __shfl_xor(su, o, 64);
        float wt = e / su;
        attn_out[((size_t)w * T + t) * S + tid] = wt;
        swt[tid] = wt;
      }
      __syncthreads();
      {  // ctx[j] = sum_s wt[s] * keys[w, s, j]; thread owns j = 2tid, 2tid+1
        const float* kb = keys + (size_t)w * S * H + 2 * tid;
        float c0 = 0.f, c1 = 0.f;
#pragma unroll 8
        for (int s = 0; s < 64; s++) {
          float2 k2 = *(const float2*)&kb[(size_t)s * H];
          float wt = swt[s];
          c0 += wt * k2.x; c1 += wt * k2.y;
        }
        sctx[2 * tid] = c0; sctx[2 * tid + 1] = c1;
      }
      __syncthreads();
      if (tid < 64) {   // wave 0 stores all 512 floats
        float* dst = ws + CTX_OFF + ((size_t)t * B + w) * 512 + tid * 8;
        store_coh_f32x4(dst, *(f32x4*)&sctx[tid * 8]);
        store_coh_f32x4(dst + 4, *(f32x4*)&sctx[tid * 8 + 4]);
      }
      if (tid == 0) {
        asm volatile("s_waitcnt vmcnt(0)" ::: "memory");
        __hip_atomic_fetch_add(&flg[(size_t)t * 320 + 256 + w], 1,
                               __ATOMIC_RELAXED, __HIP_MEMORY_SCOPE_AGENT);
      }
    }

    // ===== phase 3: gates for cols {2w, 2w+1} x 3 gates x 32 b =====
    float gh = 0.f; int c3 = 0, b3 = 0, gate = 0, l3 = 0, col = 0;
    if (tid < 192) {
      c3 = tid >> 5; b3 = tid & 31; gate = c3 >> 1; l3 = c3 & 1;
      col = gate * 512 + 2 * w + l3;
      const float* hb = hcur + b3 * H;
      const float* wr = &sWhh[c3][0];
#pragma unroll 8
      for (int k = 0; k < 512; k += 4) {
        float4 h4 = *(const float4*)&hb[k];
        gh += wr[k] * h4.x + wr[k + 1] * h4.y + wr[k + 2] * h4.z + wr[k + 3] * h4.w;
      }
      gh += b_hh[col];
    }
    {  // wait all ctx
      const int* fc = flg + (size_t)t * 320 + 256;
      if (tid < 32)
        while (load_coh_i32(&fc[tid]) == 0) __builtin_amdgcn_s_sleep(1);
    }
    __syncthreads();
    if (tid < 192) {
      const float* cb = ws + CTX_OFF + ((size_t)t * B + b3) * 512;
      const float* wi = &sWih[c3][0];
      float gic = 0.f;
#pragma unroll 8
      for (int k = 0; k < 512; k += 4) {
        float4 c4 = *(const float4*)&cb[k];
        gic += wi[k] * c4.x + wi[k + 1] * c4.y + wi[k + 2] * c4.z + wi[k + 3] * c4.w;
      }
      float gi = ws[GIE_OFF + ((size_t)t * G3 + col) * B + b3] + gic;
      if (gate == 0) ga[0][l3][b3] = gi + gh;
      else if (gate == 1) ga[1][l3][b3] = gi + gh;
      else { ga[2][l3][b3] = gi; ga[3][l3][b3] = gh; }
    }
    __syncthreads();
    if (tid < 64) {   // GRU update (wave 0)
      int b2 = tid >> 1, l2 = tid & 1;
      float r = fast_sig(ga[0][l2][b2]);
      float z = fast_sig(ga[1][l2][b2]);
      float n = fast_tanh(ga[2][l2][b2] + r * ga[3][l2][b2]);
      float hold = hcur[b2 * H + 2 * w + l2];
      float hn = (1.f - z) * n + z * hold;
      store_coh_f32(ws + HALL_OFF + (size_t)(t + 1) * B * H + b2 * H + 2 * w + l2, hn);
      HBF[((size_t)b2 * T + t) * H + 2 * w + l2] = __float2bfloat16(hn);
    }
    if (tid == 0) {
      asm volatile("s_waitcnt vmcnt(0)" ::: "memory");
      __hip_atomic_fetch_add(&flg[(size_t)t * 320 + 288 + (w >> 3)], 1,
                             __ATOMIC_RELAXED, __HIP_MEMORY_SCOPE_AGENT);
    }
  }
}

// -------------------- bf16 MFMA out-projection: [2048,512] x [32000,512]^T --------------------
__global__ __launch_bounds__(256) void k_outgemm(
    const __hip_bfloat16* __restrict__ Abf, const __hip_bfloat16* __restrict__ Bbf,
    const float* __restrict__ bias, float* __restrict__ Cmat) {
  constexpr int LDT = 40;
  __shared__ __align__(16) short As[128 * LDT];
  __shared__ __align__(16) short Bs[128 * LDT];
  int bm = blockIdx.y, bn = blockIdx.x;
  int tid = threadIdx.x;
  int lane = tid & 63, wid = tid >> 6;
  int wm = wid >> 1, wn = wid & 1;
  f32x4 acc[4][4] = {};
  int srow = tid >> 1, shalf = tid & 1;
  for (int k0 = 0; k0 < 512; k0 += 32) {
    const float4* ga = (const float4*)&Abf[(size_t)(bm * 128 + srow) * 512 + k0 + shalf * 16];
    const float4* gb = (const float4*)&Bbf[(size_t)(bn * 128 + srow) * 512 + k0 + shalf * 16];
    float4 va0 = ga[0], va1 = ga[1];
    float4 vb0 = gb[0], vb1 = gb[1];
    __syncthreads();
    *(float4*)&As[srow * LDT + shalf * 16] = va0;
    *(float4*)&As[srow * LDT + shalf * 16 + 8] = va1;
    *(float4*)&Bs[srow * LDT + shalf * 16] = vb0;
    *(float4*)&Bs[srow * LDT + shalf * 16 + 8] = vb1;
    __syncthreads();
    int kc = lane >> 4, rl = lane & 15;
    bf16x8 af[4], bfv[4];
#pragma unroll
    for (int f = 0; f < 4; f++) {
      af[f] = *(const bf16x8*)&As[(wm * 64 + f * 16 + rl) * LDT + kc * 8];
      bfv[f] = *(const bf16x8*)&Bs[(wn * 64 + f * 16 + rl) * LDT + kc * 8];
    }
#pragma unroll
    for (int i = 0; i < 4; i++)
#pragma unroll
      for (int j = 0; j < 4; j++)
        acc[i][j] = __builtin_amdgcn_mfma_f32_16x16x32_bf16(af[i], bfv[j], acc[i][j], 0, 0, 0);
  }
  int cl = lane & 15, rg = lane >> 4;
#pragma unroll
  for (int i = 0; i < 4; i++) {
    int m = bm * 128 + wm * 64 + i * 16 + rg * 4;
#pragma unroll
    for (int j = 0; j < 4; j++) {
      int n = bn * 128 + wn * 64 + j * 16 + cl;
      float bv = bias[n];
#pragma unroll
      for (int r = 0; r < 4; r++)
        Cmat[(size_t)(m + r) * V + n] = acc[i][j][r] + bv;
    }
  }
}

// -------------------- in-place log_softmax (online stats, 2 passes) --------------------
__global__ __launch_bounds__(256) void k_logsoftmax(float* __restrict__ Cmat) {
  int row = blockIdx.x;
  float* p = Cmat + (size_t)row * V;
  int tid = threadIdx.x;
  __shared__ float sm[4], ss[4];
  float m = -1e30f, s = 0.f;
  for (int i = tid * 4; i < V; i += 1024) {
    float4 v = *(const float4*)&p[i];
    float m4 = fmaxf(fmaxf(v.x, v.y), fmaxf(v.z, v.w));
    float nm = fmaxf(m, m4);
    s = s * __expf(m - nm) + __expf(v.x - nm) + __expf(v.y - nm)
      + __expf(v.z - nm) + __expf(v.w - nm);
    m = nm;
  }
  for (int o = 32; o; o >>= 1) {
    float om = __shfl_xor(m, o, 64), os = __shfl_xor(s, o, 64);
    float nm = fmaxf(m, om);
    s = s * __expf(m - nm) + os * __expf(om - nm);
    m = nm;
  }
  if ((tid & 63) == 0) { sm[tid >> 6] = m; ss[tid >> 6] = s; }
  __syncthreads();
  float M = fmaxf(fmaxf(sm[0], sm[1]), fmaxf(sm[2], sm[3]));
  float Ssum = ss[0] * __expf(sm[0] - M) + ss[1] * __expf(sm[1] - M)
             + ss[2] * __expf(sm[2] - M) + ss[3] * __expf(sm[3] - M);
  float lse = M + __logf(Ssum);
  for (int i = tid * 4; i < V; i += 1024) {
    float4 v = *(const float4*)&p[i];
    v.x -= lse; v.y -= lse; v.z -= lse; v.w -= lse;
    *(float4*)&p[i] = v;
  }
}

__global__ void k_copy_ht(const float* __restrict__ hsrc, float* __restrict__ o) {
  int i = blockIdx.x * 256 + threadIdx.x;
  if (i < B * H) o[i] = hsrc[i];
}

extern "C" void kernel_launch(void* const* d_in, const int* in_sizes, int n_in,
                              void* d_out, int out_size, void* d_ws, size_t ws_size,
                              hipStream_t stream) {
  (void)in_sizes; (void)n_in; (void)out_size; (void)ws_size;
  const float* keys = (const float*)d_in[0];
  const float* ehid = (const float*)d_in[1];
  const int* tgt    = (const int*)d_in[2];
  const float* emb  = (const float*)d_in[4];
  const float* Wa_w = (const float*)d_in[5];
  const float* Wa_b = (const float*)d_in[6];
  const float* Ua_w = (const float*)d_in[7];
  const float* Ua_b = (const float*)d_in[8];
  const float* Va_w = (const float*)d_in[9];
  const float* Va_b = (const float*)d_in[10];
  const float* W_ih = (const float*)d_in[11];
  const float* W_hh = (const float*)d_in[12];
  const float* b_ih = (const float*)d_in[13];
  const float* b_hh = (const float*)d_in[14];
  const float* out_w = (const float*)d_in[15];
  const float* out_b = (const float*)d_in[16];
  float* ws = (float*)d_ws;
  float* out = (float*)d_out;
  float* logits = out;                              // [B,T,V]
  float* ht_out = out + (size_t)B * T * V;          // [1,B,H]
  float* attn_out = ht_out + (size_t)B * H;         // [B,T,S]

  hipLaunchKernelGGL(k_init, dim3(128), dim3(256), 0, stream, ehid, tgt, ws);
  // Ua_keys = keys @ Ua_w.T + Ua_b   -> [B*S][H]
  hipLaunchKernelGGL(k_gemm_at, dim3(32, 8), dim3(256), 0, stream,
                     keys, Ua_w, 512, Ua_b, ws + UAK_OFF, (const int*)nullptr, 512, 0);
  // Gi_e = emb[tokens] @ W_ih[:, :512].T + b_ih  -> transposed [T][G3][B]
  hipLaunchKernelGGL(k_gemm_at, dim3(32, 24), dim3(256), 0, stream,
                     emb, W_ih, 1024, b_ih, ws + GIE_OFF, (const int*)(ws + ROWIDX_OFF), G3, 1);
  // persistent recurrence: ONE launch for all 64 steps
  hipLaunchKernelGGL(k_recur, dim3(256), dim3(256), 0, stream,
                     keys, Wa_w, Wa_b, Va_w, Va_b, W_ih, W_hh, b_hh, ws, attn_out);
  hipLaunchKernelGGL(k_copy_ht, dim3(64), dim3(256), 0, stream,
                     ws + HALL_OFF + (size_t)T * B * H, ht_out);
  // bf16 out_w copy into the (now dead) precompute region
  hipLaunchKernelGGL(k_conv_outw, dim3((V * H / 4 + 255) / 256), dim3(256), 0, stream,
                     out_w, (ushort*)(ws + OWBF_OFF), V * H / 4);
  hipLaunchKernelGGL(k_outgemm, dim3(250, 16), dim3(256), 0, stream,
                     (const __hip_bfloat16*)(ws + HBF_OFF),
                     (const __hip_bfloat16*)(ws + OWBF_OFF), out_b, logits);
  hipLaunchKernelGGL(k_logsoftmax, dim3(BT), dim3(256), 0, stream, logits);
}

// Round 7
// 2104.630 us; speedup vs baseline: 1.7770x; 1.2806x over previous
//
#include <hip/hip_runtime.h>
#include <hip/hip_bf16.h>
#include <math.h>

constexpr int B = 32, S = 64, T = 64, H = 512, V = 32000;
constexpr int G3 = 3 * H;     // 1536
constexpr int BT = B * T;     // 2048

// ---- workspace layout (float offsets) ----
constexpr size_t UAK_OFF    = 0;          // [B*S*H]      1,048,576
constexpr size_t GIE_OFF    = 1048576;    // [T][G3][B]   3,145,728  -> end 4,194,304
constexpr size_t KWT_OFF    = 4194304;    // [B][G3][S]   3,145,728  -> end 7,340,032
constexpr size_t SCP_OFF    = 7340032;    // [T][B][8][64] 1,048,576 -> end 8,388,608
constexpr size_t ROWIDX_OFF = 7340032;    // 2048 ints; aliases SCP (dead before SCP written)
constexpr size_t HALL_OFF   = 8388608;    // [(T+1)*B*H]  1,064,960  -> end 9,453,568
constexpr size_t HBF_OFF    = 9453568;    // bf16 [B*T*H] = 524,288 slots -> end 9,977,856
constexpr size_t FLG_OFF    = 9977856;    // T*64 ints (per t: [b*2]=hflag, [b*2+1]=sflag)
constexpr size_t OWBF_OFF   = 0;          // bf16 [V*H] = 8,192,000 slots; aliases
                                          // UAK/GIE/KWT/SCP (all dead post-recurrence)

typedef __attribute__((ext_vector_type(8))) short bf16x8;
typedef __attribute__((ext_vector_type(4))) float f32x4;

__device__ __forceinline__ float fast_tanh(float x) {
  float ax = fabsf(x);
  float e = __expf(-2.f * ax);
  float r = (1.f - e) / (1.f + e);
  return x < 0.f ? -r : r;
}
__device__ __forceinline__ float fast_sig(float x) {
  return 1.f / (1.f + __expf(-x));
}
// load/store that bypass L1+L2 (coherence point / LLC)
__device__ __forceinline__ int load_coh_i32(const int* p) {
  int v;
  asm volatile("global_load_dword %0, %1, off sc0 sc1\n\ts_waitcnt vmcnt(0)"
               : "=v"(v) : "v"(p) : "memory");
  return v;
}
__device__ __forceinline__ void store_coh_f32x4(float* p, f32x4 v) {
  asm volatile("global_store_dwordx4 %0, %1, off sc0 sc1" :: "v"(p), "v"(v) : "memory");
}

// -------------------- init: h0, token row indices, flags --------------------
__global__ void k_init(const float* __restrict__ eh, const int* __restrict__ tgt,
                       float* __restrict__ ws) {
  int i = blockIdx.x * 256 + threadIdx.x;      // grid 128*256 = 32768
  if (i < B * H) ws[HALL_OFF + i] = eh[i];
  if (i < BT) {
    int b = i / T, t = i % T;
    ((int*)(ws + ROWIDX_OFF))[i] = (t == 0) ? 0 : tgt[b * T + t - 1];
  }
  if (i < T * 64) ((int*)(ws + FLG_OFF))[i] = 0;
}

// -------------------- out_w fp32 -> bf16 (runs AFTER recurrence; aliases ws) ----
__global__ void k_conv_outw(const float* __restrict__ w, ushort* __restrict__ o, int n4) {
  int i = blockIdx.x * blockDim.x + threadIdx.x;
  if (i < n4) {
    float4 v = *(const float4*)&w[(size_t)i * 4];
    ushort4 u;
    __hip_bfloat16 h0 = __float2bfloat16(v.x); u.x = *(ushort*)&h0;
    __hip_bfloat16 h1 = __float2bfloat16(v.y); u.y = *(ushort*)&h1;
    __hip_bfloat16 h2 = __float2bfloat16(v.z); u.z = *(ushort*)&h2;
    __hip_bfloat16 h3 = __float2bfloat16(v.w); u.w = *(ushort*)&h3;
    *(ushort4*)&o[(size_t)i * 4] = u;
  }
}

// -------- fp32 tiled GEMM, k-major LDS: C = A[arow(m),:] . Bw[n,:] + bias[n] --------
// gie_t: write transposed layout C[((m%T)*G3 + n)*B + m/T]
__global__ __launch_bounds__(256) void k_gemm_at(
    const float* __restrict__ A, const float* __restrict__ Bw, int ldb,
    const float* __restrict__ bias, float* __restrict__ C,
    const int* __restrict__ rowidx, int N, int gie_t) {
  __shared__ float AsT[32][72];
  __shared__ float BsT[32][72];
  int tid = threadIdx.x;
  int bm = blockIdx.x, bn = blockIdx.y;
  int tr = tid >> 4, tc = tid & 15;
  float acc[4][4] = {};
  for (int k0 = 0; k0 < 512; k0 += 32) {
    __syncthreads();
#pragma unroll
    for (int i = 0; i < 2; i++) {
      int e = tid + i * 256;
      int row = e >> 3, c4 = (e & 7) * 4;
      int ar = bm * 64 + row;
      int arow = rowidx ? rowidx[ar] : ar;
      float4 v = *(const float4*)&A[(size_t)arow * 512 + k0 + c4];
      AsT[c4 + 0][row] = v.x; AsT[c4 + 1][row] = v.y;
      AsT[c4 + 2][row] = v.z; AsT[c4 + 3][row] = v.w;
      float4 u = *(const float4*)&Bw[(size_t)(bn * 64 + row) * ldb + k0 + c4];
      BsT[c4 + 0][row] = u.x; BsT[c4 + 1][row] = u.y;
      BsT[c4 + 2][row] = u.z; BsT[c4 + 3][row] = u.w;
    }
    __syncthreads();
#pragma unroll
    for (int kk = 0; kk < 32; kk++) {
      float4 a4 = *(const float4*)&AsT[kk][tr * 4];
      float4 b4 = *(const float4*)&BsT[kk][tc * 4];
      acc[0][0] += a4.x * b4.x; acc[0][1] += a4.x * b4.y; acc[0][2] += a4.x * b4.z; acc[0][3] += a4.x * b4.w;
      acc[1][0] += a4.y * b4.x; acc[1][1] += a4.y * b4.y; acc[1][2] += a4.y * b4.z; acc[1][3] += a4.y * b4.w;
      acc[2][0] += a4.z * b4.x; acc[2][1] += a4.z * b4.y; acc[2][2] += a4.z * b4.z; acc[2][3] += a4.z * b4.w;
      acc[3][0] += a4.w * b4.x; acc[3][1] += a4.w * b4.y; acc[3][2] += a4.w * b4.z; acc[3][3] += a4.w * b4.w;
    }
  }
#pragma unroll
  for (int i = 0; i < 4; i++) {
    int m = bm * 64 + tr * 4 + i;
#pragma unroll
    for (int j = 0; j < 4; j++) {
      int n = bn * 64 + tc * 4 + j;
      float val = acc[i][j] + bias[n];
      if (gie_t) C[((size_t)(m % T) * G3 + n) * B + (m / T)] = val;
      else       C[(size_t)m * N + n] = val;
    }
  }
}

// -------- KWT[b, col, s] = sum_k W_ih[col, 512+k] * keys[b*64+s, k] --------
__global__ __launch_bounds__(256) void k_gemm_kwt(
    const float* __restrict__ W_ih, const float* __restrict__ keys,
    float* __restrict__ KWT) {
  __shared__ float AsT[32][72];
  __shared__ float BsT[32][72];
  int tid = threadIdx.x;
  int bm = blockIdx.x, b = blockIdx.y;
  int tr = tid >> 4, tc = tid & 15;
  float acc[4][4] = {};
  for (int k0 = 0; k0 < 512; k0 += 32) {
    __syncthreads();
#pragma unroll
    for (int i = 0; i < 2; i++) {
      int e = tid + i * 256;
      int row = e >> 3, c4 = (e & 7) * 4;
      float4 v = *(const float4*)&W_ih[(size_t)(bm * 64 + row) * 1024 + 512 + k0 + c4];
      AsT[c4 + 0][row] = v.x; AsT[c4 + 1][row] = v.y;
      AsT[c4 + 2][row] = v.z; AsT[c4 + 3][row] = v.w;
      float4 u = *(const float4*)&keys[(size_t)(b * 64 + row) * 512 + k0 + c4];
      BsT[c4 + 0][row] = u.x; BsT[c4 + 1][row] = u.y;
      BsT[c4 + 2][row] = u.z; BsT[c4 + 3][row] = u.w;
    }
    __syncthreads();
#pragma unroll
    for (int kk = 0; kk < 32; kk++) {
      float4 a4 = *(const float4*)&AsT[kk][tr * 4];
      float4 b4 = *(const float4*)&BsT[kk][tc * 4];
      acc[0][0] += a4.x * b4.x; acc[0][1] += a4.x * b4.y; acc[0][2] += a4.x * b4.z; acc[0][3] += a4.x * b4.w;
      acc[1][0] += a4.y * b4.x; acc[1][1] += a4.y * b4.y; acc[1][2] += a4.y * b4.z; acc[1][3] += a4.y * b4.w;
      acc[2][0] += a4.z * b4.x; acc[2][1] += a4.z * b4.y; acc[2][2] += a4.z * b4.z; acc[2][3] += a4.z * b4.w;
      acc[3][0] += a4.w * b4.x; acc[3][1] += a4.w * b4.y; acc[3][2] += a4.w * b4.z; acc[3][3] += a4.w * b4.w;
    }
  }
#pragma unroll
  for (int i = 0; i < 4; i++) {
    int m = bm * 64 + tr * 4 + i;
#pragma unroll
    for (int j = 0; j < 4; j++)
      KWT[((size_t)b * G3 + m) * S + tc * 4 + j] = acc[i][j];
  }
}

// -------------------- persistent recurrence v3: per-batch pipelines --------------------
// 256 WGs x 256 thr. WG w = (b=w>>3, cb=w&7): owns batch b, h/q-col slice
// [cb*64, cb*64+64), gate cols {g*512 + cb*64 + jl}. cb == w%8 -> same-cb WGs
// share an XCD (Wa/W_hh slices L2-resident). Per WG static LDS: KWT slice
// (192x64, 50KB) + UAK slice (64x64, 17KB) + Va/bias slices.
// Per step: poll hflag(b)==8 -> stage h[b] -> q-slice -> score partials ->
// SCP store + sflag -> gh (overlaps peers' handshakes) -> poll sflag(b)==8 ->
// softmax (redundant x8, trivial) -> gi = GIE + KWT.wt -> GRU -> h-slice store
// + hflag. Only per-b syncs (8 increments each), 2 per step, no global barrier.
__global__ __launch_bounds__(256) void k_recur(
    const float* __restrict__ Wa_w, const float* __restrict__ Wa_b,
    const float* __restrict__ Va_w, const float* __restrict__ Va_b,
    const float* __restrict__ W_hh, const float* __restrict__ b_hh,
    float* __restrict__ ws, float* __restrict__ attn_out) {
  const int w = blockIdx.x;
  const int tid = threadIdx.x;
  const int b = w >> 3, cb = w & 7;
  const int j0 = cb * 64;
  int* flg = (int*)(ws + FLG_OFF);
  __hip_bfloat16* HBF = (__hip_bfloat16*)(ws + HBF_OFF);

  __shared__ float sKWT[192][65];   // 49.9 KB
  __shared__ float sUAK[64][65];    // 16.6 KB
  __shared__ float sh[512];
  __shared__ float sq[64];
  __shared__ float qp[64][4];
  __shared__ float spp[64][4];
  __shared__ float sps[64];
  __shared__ float swt[64];
  __shared__ float sga[4][64];
  __shared__ float shn[64];
  __shared__ float sVa[64];

  // ---- one-time staging ----
#pragma unroll
  for (int g = 0; g < 3; g++) {
    int jl = tid >> 2, part = tid & 3;
    const float* src = ws + KWT_OFF + ((size_t)b * G3 + g * 512 + j0 + jl) * 64 + part * 16;
    float* dst = &sKWT[g * 64 + jl][part * 16];
#pragma unroll
    for (int i = 0; i < 16; i += 4) {
      float4 v = *(const float4*)&src[i];
      dst[i] = v.x; dst[i + 1] = v.y; dst[i + 2] = v.z; dst[i + 3] = v.w;
    }
  }
  {
    int s = tid >> 2, part = tid & 3;
    const float* src = ws + UAK_OFF + ((size_t)(b * 64 + s)) * H + j0 + part * 16;
    float* dst = &sUAK[s][part * 16];
#pragma unroll
    for (int i = 0; i < 16; i += 4) {
      float4 v = *(const float4*)&src[i];
      dst[i] = v.x; dst[i + 1] = v.y; dst[i + 2] = v.z; dst[i + 3] = v.w;
    }
  }
  if (tid < 64) sVa[tid] = Va_w[j0 + tid];
  __syncthreads();

  for (int t = 0; t < T; ++t) {
    // ---- wait for h_t (written by the 8 WGs of batch b at step t-1) ----
    if (t > 0) {
      if (tid == 0)
        while (load_coh_i32(&flg[(t - 1) * 64 + b * 2]) != 8) __builtin_amdgcn_s_sleep(1);
    }
    __syncthreads();
    const float* hcur = ws + HALL_OFF + (size_t)t * B * H + b * H;
    sh[tid] = hcur[tid];
    sh[tid + 256] = hcur[tid + 256];
    __syncthreads();

    // ---- q slice: q[j0+jl] = Wa[j0+jl,:] . h + bias ----
    {
      int jl = tid >> 2, kq = tid & 3;
      const float* wrow = Wa_w + (size_t)(j0 + jl) * H + kq * 128;
      const float* hv = sh + kq * 128;
      float acc = 0.f;
#pragma unroll
      for (int i = 0; i < 128; i += 4) {
        float4 w4 = *(const float4*)&wrow[i];
        acc += w4.x * hv[i] + w4.y * hv[i + 1] + w4.z * hv[i + 2] + w4.w * hv[i + 3];
      }
      qp[jl][kq] = acc;
    }
    __syncthreads();
    if (tid < 64)
      sq[tid] = qp[tid][0] + qp[tid][1] + qp[tid][2] + qp[tid][3] + Wa_b[j0 + tid];
    __syncthreads();
    // ---- score partials over this WG's 64-j slice ----
    {
      int s = tid >> 2, jc = tid & 3;
      float accs = 0.f;
#pragma unroll
      for (int i = 0; i < 16; i++) {
        int j = jc * 16 + i;
        accs += sVa[j] * fast_tanh(sq[j] + sUAK[s][j]);
      }
      spp[s][jc] = accs;
    }
    __syncthreads();
    if (tid < 64) {
      float v = spp[tid][0] + spp[tid][1] + spp[tid][2] + spp[tid][3];
      if (cb == 0) v += Va_b[0];
      sps[tid] = v;
    }
    __syncthreads();
    if (tid < 16) {
      float* dst = ws + SCP_OFF + (((size_t)t * B + b) * 8 + cb) * 64 + tid * 4;
      store_coh_f32x4(dst, *(f32x4*)&sps[tid * 4]);
    }
    if (tid == 0) {
      asm volatile("s_waitcnt vmcnt(0)" ::: "memory");
      __hip_atomic_fetch_add(&flg[t * 64 + b * 2 + 1], 1,
                             __ATOMIC_RELAXED, __HIP_MEMORY_SCOPE_AGENT);
    }

    // ---- gh = W_hh[col,:] . h + b_hh (overlaps peers' score phase) ----
    float gh = 0.f;
    if (tid < 192) {
      int gate = tid >> 6, jl = tid & 63;
      int col = gate * 512 + j0 + jl;
      const float* wr = W_hh + (size_t)col * H;
#pragma unroll 8
      for (int k = 0; k < 512; k += 4) {
        float4 w4 = *(const float4*)&wr[k];
        gh += w4.x * sh[k] + w4.y * sh[k + 1] + w4.z * sh[k + 2] + w4.w * sh[k + 3];
      }
      gh += b_hh[col];
    }
    // ---- wait all 8 score slices of batch b ----
    if (tid == 0)
      while (load_coh_i32(&flg[t * 64 + b * 2 + 1]) != 8) __builtin_amdgcn_s_sleep(1);
    __syncthreads();
    // ---- softmax (redundant per WG of b; 64 elements) ----
    if (tid < 64) {
      const float* spg = ws + SCP_OFF + ((size_t)t * B + b) * 512 + tid;
      float v = spg[0] + spg[64] + spg[128] + spg[192]
              + spg[256] + spg[320] + spg[384] + spg[448];
      float m = v;
      for (int o = 32; o; o >>= 1) m = fmaxf(m, __shfl_xor(m, o, 64));
      float e = __expf(v - m);
      float su = e;
      for (int o = 32; o; o >>= 1) su += __shfl_xor(su, o, 64);
      float wt = e / su;
      swt[tid] = wt;
      if (cb == 0) attn_out[((size_t)b * T + t) * S + tid] = wt;
    }
    __syncthreads();
    // ---- gi = GIE + KWT . wt ; combine ----
    if (tid < 192) {
      int gate = tid >> 6, jl = tid & 63;
      int col = gate * 512 + j0 + jl;
      float gic = 0.f;
#pragma unroll
      for (int s = 0; s < 64; s += 4) {
        gic += swt[s] * sKWT[tid][s] + swt[s + 1] * sKWT[tid][s + 1]
             + swt[s + 2] * sKWT[tid][s + 2] + swt[s + 3] * sKWT[tid][s + 3];
      }
      float gi = ws[GIE_OFF + ((size_t)t * G3 + col) * B + b] + gic;
      if (gate == 0) sga[0][jl] = gi + gh;
      else if (gate == 1) sga[1][jl] = gi + gh;
      else { sga[2][jl] = gi; sga[3][jl] = gh; }
    }
    __syncthreads();
    // ---- GRU update for the 64 owned h-cols ----
    if (tid < 64) {
      float r = fast_sig(sga[0][tid]);
      float z = fast_sig(sga[1][tid]);
      float n = fast_tanh(sga[2][tid] + r * sga[3][tid]);
      float hold = sh[j0 + tid];
      float hn = (1.f - z) * n + z * hold;
      shn[tid] = hn;
      HBF[((size_t)b * T + t) * H + j0 + tid] = __float2bfloat16(hn);
    }
    __syncthreads();
    if (tid < 16)
      store_coh_f32x4(ws + HALL_OFF + (size_t)(t + 1) * B * H + b * H + j0 + tid * 4,
                      *(f32x4*)&shn[tid * 4]);
    if (tid == 0) {
      asm volatile("s_waitcnt vmcnt(0)" ::: "memory");
      __hip_atomic_fetch_add(&flg[t * 64 + b * 2], 1,
                             __ATOMIC_RELAXED, __HIP_MEMORY_SCOPE_AGENT);
    }
  }
}

// -------------------- bf16 MFMA out-projection: [2048,512] x [32000,512]^T --------------------
__global__ __launch_bounds__(256) void k_outgemm(
    const __hip_bfloat16* __restrict__ Abf, const __hip_bfloat16* __restrict__ Bbf,
    const float* __restrict__ bias, float* __restrict__ Cmat) {
  constexpr int LDT = 40;
  __shared__ __align__(16) short As[128 * LDT];
  __shared__ __align__(16) short Bs[128 * LDT];
  int bm = blockIdx.y, bn = blockIdx.x;
  int tid = threadIdx.x;
  int lane = tid & 63, wid = tid >> 6;
  int wm = wid >> 1, wn = wid & 1;
  f32x4 acc[4][4] = {};
  int srow = tid >> 1, shalf = tid & 1;
  for (int k0 = 0; k0 < 512; k0 += 32) {
    const float4* ga = (const float4*)&Abf[(size_t)(bm * 128 + srow) * 512 + k0 + shalf * 16];
    const float4* gb = (const float4*)&Bbf[(size_t)(bn * 128 + srow) * 512 + k0 + shalf * 16];
    float4 va0 = ga[0], va1 = ga[1];
    float4 vb0 = gb[0], vb1 = gb[1];
    __syncthreads();
    *(float4*)&As[srow * LDT + shalf * 16] = va0;
    *(float4*)&As[srow * LDT + shalf * 16 + 8] = va1;
    *(float4*)&Bs[srow * LDT + shalf * 16] = vb0;
    *(float4*)&Bs[srow * LDT + shalf * 16 + 8] = vb1;
    __syncthreads();
    int kc = lane >> 4, rl = lane & 15;
    bf16x8 af[4], bfv[4];
#pragma unroll
    for (int f = 0; f < 4; f++) {
      af[f] = *(const bf16x8*)&As[(wm * 64 + f * 16 + rl) * LDT + kc * 8];
      bfv[f] = *(const bf16x8*)&Bs[(wn * 64 + f * 16 + rl) * LDT + kc * 8];
    }
#pragma unroll
    for (int i = 0; i < 4; i++)
#pragma unroll
      for (int j = 0; j < 4; j++)
        acc[i][j] = __builtin_amdgcn_mfma_f32_16x16x32_bf16(af[i], bfv[j], acc[i][j], 0, 0, 0);
  }
  int cl = lane & 15, rg = lane >> 4;
#pragma unroll
  for (int i = 0; i < 4; i++) {
    int m = bm * 128 + wm * 64 + i * 16 + rg * 4;
#pragma unroll
    for (int j = 0; j < 4; j++) {
      int n = bn * 128 + wn * 64 + j * 16 + cl;
      float bv = bias[n];
#pragma unroll
      for (int r = 0; r < 4; r++)
        Cmat[(size_t)(m + r) * V + n] = acc[i][j][r] + bv;
    }
  }
}

// -------------------- in-place log_softmax (online stats, 2 passes) --------------------
__global__ __launch_bounds__(256) void k_logsoftmax(float* __restrict__ Cmat) {
  int row = blockIdx.x;
  float* p = Cmat + (size_t)row * V;
  int tid = threadIdx.x;
  __shared__ float sm[4], ss[4];
  float m = -1e30f, s = 0.f;
  for (int i = tid * 4; i < V; i += 1024) {
    float4 v = *(const float4*)&p[i];
    float m4 = fmaxf(fmaxf(v.x, v.y), fmaxf(v.z, v.w));
    float nm = fmaxf(m, m4);
    s = s * __expf(m - nm) + __expf(v.x - nm) + __expf(v.y - nm)
      + __expf(v.z - nm) + __expf(v.w - nm);
    m = nm;
  }
  for (int o = 32; o; o >>= 1) {
    float om = __shfl_xor(m, o, 64), os = __shfl_xor(s, o, 64);
    float nm = fmaxf(m, om);
    s = s * __expf(m - nm) + os * __expf(om - nm);
    m = nm;
  }
  if ((tid & 63) == 0) { sm[tid >> 6] = m; ss[tid >> 6] = s; }
  __syncthreads();
  float M = fmaxf(fmaxf(sm[0], sm[1]), fmaxf(sm[2], sm[3]));
  float Ssum = ss[0] * __expf(sm[0] - M) + ss[1] * __expf(sm[1] - M)
             + ss[2] * __expf(sm[2] - M) + ss[3] * __expf(sm[3] - M);
  float lse = M + __logf(Ssum);
  for (int i = tid * 4; i < V; i += 1024) {
    float4 v = *(const float4*)&p[i];
    v.x -= lse; v.y -= lse; v.z -= lse; v.w -= lse;
    *(float4*)&p[i] = v;
  }
}

__global__ void k_copy_ht(const float* __restrict__ hsrc, float* __restrict__ o) {
  int i = blockIdx.x * 256 + threadIdx.x;
  if (i < B * H) o[i] = hsrc[i];
}

extern "C" void kernel_launch(void* const* d_in, const int* in_sizes, int n_in,
                              void* d_out, int out_size, void* d_ws, size_t ws_size,
                              hipStream_t stream) {
  (void)in_sizes; (void)n_in; (void)out_size; (void)ws_size;
  const float* keys = (const float*)d_in[0];
  const float* ehid = (const float*)d_in[1];
  const int* tgt    = (const int*)d_in[2];
  const float* emb  = (const float*)d_in[4];
  const float* Wa_w = (const float*)d_in[5];
  const float* Wa_b = (const float*)d_in[6];
  const float* Ua_w = (const float*)d_in[7];
  const float* Ua_b = (const float*)d_in[8];
  const float* Va_w = (const float*)d_in[9];
  const float* Va_b = (const float*)d_in[10];
  const float* W_ih = (const float*)d_in[11];
  const float* W_hh = (const float*)d_in[12];
  const float* b_ih = (const float*)d_in[13];
  const float* b_hh = (const float*)d_in[14];
  const float* out_w = (const float*)d_in[15];
  const float* out_b = (const float*)d_in[16];
  float* ws = (float*)d_ws;
  float* out = (float*)d_out;
  float* logits = out;                              // [B,T,V]
  float* ht_out = out + (size_t)B * T * V;          // [1,B,H]
  float* attn_out = ht_out + (size_t)B * H;         // [B,T,S]

  hipLaunchKernelGGL(k_init, dim3(128), dim3(256), 0, stream, ehid, tgt, ws);
  // Ua_keys = keys @ Ua_w.T + Ua_b   -> [B*S][H]
  hipLaunchKernelGGL(k_gemm_at, dim3(32, 8), dim3(256), 0, stream,
                     keys, Ua_w, 512, Ua_b, ws + UAK_OFF, (const int*)nullptr, 512, 0);
  // Gi_e = emb[tokens] @ W_ih[:, :512].T + b_ih  -> transposed [T][G3][B]
  hipLaunchKernelGGL(k_gemm_at, dim3(32, 24), dim3(256), 0, stream,
                     emb, W_ih, 1024, b_ih, ws + GIE_OFF, (const int*)(ws + ROWIDX_OFF), G3, 1);
  // KWT[b,col,s] = W_ih_ctx @ keys[b]^T
  hipLaunchKernelGGL(k_gemm_kwt, dim3(24, 32), dim3(256), 0, stream,
                     W_ih, keys, ws + KWT_OFF);
  // persistent recurrence: ONE launch, per-batch pipelines
  hipLaunchKernelGGL(k_recur, dim3(256), dim3(256), 0, stream,
                     Wa_w, Wa_b, Va_w, Va_b, W_hh, b_hh, ws, attn_out);
  hipLaunchKernelGGL(k_copy_ht, dim3(64), dim3(256), 0, stream,
                     ws + HALL_OFF + (size_t)T * B * H, ht_out);
  // bf16 out_w copy into the (now dead) precompute region
  hipLaunchKernelGGL(k_conv_outw, dim3((V * H / 4 + 255) / 256), dim3(256), 0, stream,
                     out_w, (ushort*)(ws + OWBF_OFF), V * H / 4);
  hipLaunchKernelGGL(k_outgemm, dim3(250, 16), dim3(256), 0, stream,
                     (const __hip_bfloat16*)(ws + HBF_OFF),
                     (const __hip_bfloat16*)(ws + OWBF_OFF), out_b, logits);
  hipLaunchKernelGGL(k_logsoftmax, dim3(BT), dim3(256), 0, stream, logits);
}